// Round 4
// baseline (105.179 us; speedup 1.0000x reference)
//
#include <hip/hip_runtime.h>

#define THRESH 0.5f
#define ALPHA 0.5f
#define BLOCK 256

// Fully-coalesced streaming reduction with register double-buffer prefetch.
//
// Layout: rows of 5 floats. A float4 with index j has phase p = j % 5;
// channel of slot s is (4p+s) % 5. Each float4 holds at most one c0 (slot
// s == p, p < 4). Box slots with s < p belong to the PREVIOUS row, whose
// mask comes from the previous float4 (lane-1) -> one __shfl_up carry.
// Tiles of 320 float4 (5 regs x 64 lanes) keep boundaries on row-group
// boundaries (320 % 5 == 0) -> no cross-tile carry.
//
// R3 post-mortem: L3-resident replays ran at the same speed as HBM-fed
// ones with VALUBusy 15% -> latency-bound (per-tile L+C serialization).
// R4: prefetch tile t+1's 10 loads before computing tile t (static A/B
// buffers; 20 loads in flight per wave).
__global__ void mloss_partial(const float4* __restrict__ xv,
                              const float4* __restrict__ yv,
                              const float* __restrict__ x,
                              const float* __restrict__ y,
                              float4* __restrict__ part,
                              int ntiles, int nrows) {
    float cnt = 0.f, s_se = 0.f, s_bce = 0.f, s_bg = 0.f;
    const int lane   = threadIdx.x & 63;
    const int gwave  = (blockIdx.x * BLOCK + threadIdx.x) >> 6;
    const int nwaves = (gridDim.x * BLOCK) >> 6;

    // Loop-invariant per-lane phases: p[k] = (lane + 64k) % 5.
    int p[5];
    {
        const int add[5] = {0, 4, 3, 2, 1};   // (64k) % 5
        int lm5 = lane % 5;
        #pragma unroll
        for (int k = 0; k < 5; ++k) {
            int v = lm5 + add[k];
            p[k] = (v >= 5) ? v - 5 : v;
        }
    }

    auto load = [&](float4 (&X)[5], float4 (&Y)[5], int tile) {
        size_t f0 = (size_t)tile * 320 + lane;
        #pragma unroll
        for (int k = 0; k < 5; ++k) {
            X[k] = xv[f0 + 64 * k];           // perfectly coalesced
            Y[k] = yv[f0 + 64 * k];
        }
    };

    auto compute = [&](const float4 (&X)[5], const float4 (&Y)[5]) {
        float carry = 0.f;                    // my_m of (reg k-1, lane 63)
        #pragma unroll
        for (int k = 0; k < 5; ++k) {
            const int pk = p[k];
            const float4 Xk = X[k], Yk = Y[k];

            // c0 (p,t) pair of this float4 (slot pk; pk==4 -> dummy slot 3,
            // value in (0.01,0.99) keeps transcendentals finite; zeroed below).
            float my_t = (pk == 0) ? Yk.x : (pk == 1) ? Yk.y : (pk == 2) ? Yk.z : Yk.w;
            float my_p = (pk == 0) ? Xk.x : (pk == 1) ? Xk.y : (pk == 2) ? Xk.z : Xk.w;
            float my_m = (my_t > THRESH) ? 1.f : 0.f;

            float pm_up  = __shfl_up(my_m, 1);
            float prev_m = (lane == 0) ? carry : pm_up;
            carry = __shfl(my_m, 63);

            float has = (pk < 4) ? 1.f : 0.f;
            float l1m = __logf(1.f - my_p);   // log(1-p); p<=0.99 -> exact enough
            float lg  = __logf(my_p);
            s_bg -= has * l1m;
            float hm = has * my_m;
            cnt += hm;
            s_bce -= hm * (my_t * lg + (1.f - my_t) * l1m);

            // Box slots: w = 0 if c0 slot, else mask of the owning row.
            float d, w;
            d = Xk.x - Yk.x; w = (pk == 0) ? 0.f : ((0 < pk) ? prev_m : my_m); s_se += w * d * d;
            d = Xk.y - Yk.y; w = (pk == 1) ? 0.f : ((1 < pk) ? prev_m : my_m); s_se += w * d * d;
            d = Xk.z - Yk.z; w = (pk == 2) ? 0.f : ((2 < pk) ? prev_m : my_m); s_se += w * d * d;
            d = Xk.w - Yk.w; w = (pk == 3) ? 0.f : ((3 < pk) ? prev_m : my_m); s_se += w * d * d;
        }
    };

    // Software-pipelined main loop: load next tile before computing current.
    float4 XA[5], YA[5], XB[5], YB[5];
    int t = gwave;
    bool haveA = (t < ntiles);
    if (haveA) load(XA, YA, t);
    while (haveA) {
        int tn = t + nwaves;
        bool haveB = (tn < ntiles);
        if (haveB) load(XB, YB, tn);
        compute(XA, YA);
        if (!haveB) break;
        t = tn + nwaves;
        haveA = (t < ntiles);
        if (haveA) load(XA, YA, t);
        compute(XB, YB);
    }

    // Generic scalar tail (zero iterations for this shape).
    for (int r = ntiles * 256 + blockIdx.x * BLOCK + threadIdx.x; r < nrows;
         r += gridDim.x * BLOCK) {
        const float* xr = x + (size_t)r * 5;
        const float* yr = y + (size_t)r * 5;
        float pp = xr[0], tt = yr[0];
        float m = (tt > THRESH) ? 1.f : 0.f;
        float l1m = __logf(1.f - pp);
        s_bg -= l1m;
        cnt += m;
        s_bce -= m * (tt * __logf(pp) + (1.f - tt) * l1m);
        float d1 = xr[1]-yr[1], d2 = xr[2]-yr[2], d3 = xr[3]-yr[3], d4 = xr[4]-yr[4];
        s_se += m * (d1*d1 + d2*d2 + d3*d3 + d4*d4);
    }

    // Wave-64 butterfly reduce.
    #pragma unroll
    for (int off = 32; off > 0; off >>= 1) {
        cnt   += __shfl_down(cnt,   off);
        s_se  += __shfl_down(s_se,  off);
        s_bce += __shfl_down(s_bce, off);
        s_bg  += __shfl_down(s_bg,  off);
    }

    __shared__ float4 lds[BLOCK / 64];
    const int wid = threadIdx.x >> 6;
    if ((threadIdx.x & 63) == 0)
        lds[wid] = make_float4(cnt, s_se, s_bce, s_bg);
    __syncthreads();
    if (threadIdx.x == 0) {
        float4 a = lds[0];
        #pragma unroll
        for (int w = 1; w < BLOCK / 64; ++w) {
            a.x += lds[w].x; a.y += lds[w].y; a.z += lds[w].z; a.w += lds[w].w;
        }
        part[blockIdx.x] = a;                 // unconditional: deterministic
    }
}

// Stage 2: one block reduces the per-block partials and emits the scalar.
__global__ void mloss_final(const float4* __restrict__ part, int nparts,
                            float* __restrict__ out, float inv_total) {
    float cnt = 0.f, s_se = 0.f, s_bce = 0.f, s_bg = 0.f;
    for (int i = threadIdx.x; i < nparts; i += BLOCK) {
        float4 v = part[i];
        cnt += v.x; s_se += v.y; s_bce += v.z; s_bg += v.w;
    }
    #pragma unroll
    for (int off = 32; off > 0; off >>= 1) {
        cnt   += __shfl_down(cnt,   off);
        s_se  += __shfl_down(s_se,  off);
        s_bce += __shfl_down(s_bce, off);
        s_bg  += __shfl_down(s_bg,  off);
    }
    __shared__ float4 lds[BLOCK / 64];
    const int wid = threadIdx.x >> 6;
    if ((threadIdx.x & 63) == 0)
        lds[wid] = make_float4(cnt, s_se, s_bce, s_bg);
    __syncthreads();
    if (threadIdx.x == 0) {
        float4 a = lds[0];
        #pragma unroll
        for (int w = 1; w < BLOCK / 64; ++w) {
            a.x += lds[w].x; a.y += lds[w].y; a.z += lds[w].z; a.w += lds[w].w;
        }
        float f = a.x;
        float scale = 1.f + 1.f / f;
        float diff_box = scale * a.y / (f * 4.f);
        float diff_c   = scale * a.z / f;
        float diff_bg  = ALPHA * a.w * inv_total;
        out[0] = diff_box + diff_c + diff_bg;
    }
}

extern "C" void kernel_launch(void* const* d_in, const int* in_sizes, int n_in,
                              void* d_out, int out_size, void* d_ws, size_t ws_size,
                              hipStream_t stream) {
    const float* x = (const float*)d_in[0];
    const float* y = (const float*)d_in[1];
    float* out   = (float*)d_out;
    float4* part = (float4*)d_ws;

    int total  = in_sizes[0];        // B*N*C = 27,688,960
    int nrows  = total / 5;          // 5,537,792
    int ntiles = total / 1280;       // 21,632 tiles of 320 float4 (exact here)

    // 2 tiles per wave (both prefetched): grid = 2704 for this shape.
    int waves_needed = (ntiles + 1) / 2;
    int grid = (waves_needed + 3) / 4;         // 4 waves per 256-thread block
    if (grid < 256) grid = 256;
    if (grid > 4096) grid = 4096;
    int wscap = (int)(ws_size / sizeof(float4));
    if (grid > wscap) grid = wscap;

    mloss_partial<<<grid, BLOCK, 0, stream>>>((const float4*)x, (const float4*)y,
                                              x, y, part, ntiles, nrows);
    mloss_final<<<1, BLOCK, 0, stream>>>(part, grid, out, 1.0f / (float)nrows);
}

// Round 5
// 41.659 us; speedup vs baseline: 2.5247x; 2.5247x over previous
//
#include <hip/hip_runtime.h>

#define THRESH 0.5f
#define ALPHA 0.5f
#define BLOCK 256

// Fully-coalesced streaming reduction, 2 tiles/wave, all loads issued up front.
//
// Layout: rows of 5 floats. A float4 with index j has phase p = j % 5;
// channel of slot s is (4p+s) % 5. Each float4 holds at most one c0 (slot
// s == p, p < 4). Box slots with s < p belong to the PREVIOUS row, whose
// mask comes from the previous float4 (lane-1) -> one __shfl_up carry.
// Tiles of 320 float4 (5 regs x 64 lanes) keep boundaries on row-group
// boundaries (320 % 5 == 0) -> no cross-tile carry, and per-lane phases
// p[k] = (lane + 64k) % 5 are identical for every tile.
//
// R4 post-mortem: rotating prefetch buffers + compiler's default VGPR=64
// cap -> 230 MB scratch spill (WRITE_SIZE), 105us. R5: __launch_bounds__
// lifts the cap; straight-line exact path (every wave owns exactly 2
// consecutive tiles, loads unconditional) keeps buffers in registers.
__global__ __launch_bounds__(BLOCK, 3)
void mloss_partial(const float4* __restrict__ xv,
                   const float4* __restrict__ yv,
                   const float* __restrict__ x,
                   const float* __restrict__ y,
                   float4* __restrict__ part,
                   int ntiles, int nrows) {
    float cnt = 0.f, s_se = 0.f, s_bce = 0.f, s_bg = 0.f;
    const int lane   = threadIdx.x & 63;
    const int gwave  = (blockIdx.x * BLOCK + threadIdx.x) >> 6;
    const int nwaves = (gridDim.x * BLOCK) >> 6;

    // Loop-invariant per-lane phases: p[k] = (lane + 64k) % 5.
    int p[5];
    {
        const int add[5] = {0, 4, 3, 2, 1};   // (64k) % 5
        int lm5 = lane % 5;
        #pragma unroll
        for (int k = 0; k < 5; ++k) {
            int v = lm5 + add[k];
            p[k] = (v >= 5) ? v - 5 : v;
        }
    }

    auto compute = [&](const float4 (&X)[5], const float4 (&Y)[5]) {
        float carry = 0.f;                    // my_m of (reg k-1, lane 63)
        #pragma unroll
        for (int k = 0; k < 5; ++k) {
            const int pk = p[k];
            const float4 Xk = X[k], Yk = Y[k];

            // c0 (p,t) pair of this float4 (slot pk; pk==4 -> dummy slot 3,
            // value in (0.01,0.99) keeps transcendentals finite; zeroed below).
            float my_t = (pk == 0) ? Yk.x : (pk == 1) ? Yk.y : (pk == 2) ? Yk.z : Yk.w;
            float my_p = (pk == 0) ? Xk.x : (pk == 1) ? Xk.y : (pk == 2) ? Xk.z : Xk.w;
            float my_m = (my_t > THRESH) ? 1.f : 0.f;

            float pm_up  = __shfl_up(my_m, 1);
            float prev_m = (lane == 0) ? carry : pm_up;
            carry = __shfl(my_m, 63);

            float has = (pk < 4) ? 1.f : 0.f;
            float l1m = __logf(1.f - my_p);   // log(1-p); p<=0.99 -> exact enough
            float lg  = __logf(my_p);
            s_bg -= has * l1m;
            float hm = has * my_m;
            cnt += hm;
            s_bce -= hm * (my_t * lg + (1.f - my_t) * l1m);

            // Box slots: w = 0 if c0 slot, else mask of the owning row.
            float d, w;
            d = Xk.x - Yk.x; w = (pk == 0) ? 0.f : ((0 < pk) ? prev_m : my_m); s_se += w * d * d;
            d = Xk.y - Yk.y; w = (pk == 1) ? 0.f : ((1 < pk) ? prev_m : my_m); s_se += w * d * d;
            d = Xk.z - Yk.z; w = (pk == 2) ? 0.f : ((2 < pk) ? prev_m : my_m); s_se += w * d * d;
            d = Xk.w - Yk.w; w = (pk == 3) ? 0.f : ((3 < pk) ? prev_m : my_m); s_se += w * d * d;
        }
    };

    if (ntiles == 2 * nwaves) {
        // Exact path: wave owns tiles 2w and 2w+1 (adjacent 10 KB spans).
        // All 20 loads issue before any use; tile-B loads stay in flight
        // (vmcnt(10)) while tile A computes.
        size_t fA = (size_t)(2 * gwave) * 320 + lane;
        float4 XA[5], YA[5], XB[5], YB[5];
        #pragma unroll
        for (int k = 0; k < 5; ++k) {
            XA[k] = xv[fA + 64 * k];
            YA[k] = yv[fA + 64 * k];
        }
        #pragma unroll
        for (int k = 0; k < 5; ++k) {
            XB[k] = xv[fA + 320 + 64 * k];
            YB[k] = yv[fA + 320 + 64 * k];
        }
        compute(XA, YA);
        compute(XB, YB);
    } else {
        // Generic fallback (any shape): strided tile loop.
        for (int tile = gwave; tile < ntiles; tile += nwaves) {
            size_t f0 = (size_t)tile * 320 + lane;
            float4 X[5], Y[5];
            #pragma unroll
            for (int k = 0; k < 5; ++k) {
                X[k] = xv[f0 + 64 * k];
                Y[k] = yv[f0 + 64 * k];
            }
            compute(X, Y);
        }
        // Scalar tail.
        for (int r = ntiles * 256 + blockIdx.x * BLOCK + threadIdx.x; r < nrows;
             r += gridDim.x * BLOCK) {
            const float* xr = x + (size_t)r * 5;
            const float* yr = y + (size_t)r * 5;
            float pp = xr[0], tt = yr[0];
            float m = (tt > THRESH) ? 1.f : 0.f;
            float l1m = __logf(1.f - pp);
            s_bg -= l1m;
            cnt += m;
            s_bce -= m * (tt * __logf(pp) + (1.f - tt) * l1m);
            float d1 = xr[1]-yr[1], d2 = xr[2]-yr[2], d3 = xr[3]-yr[3], d4 = xr[4]-yr[4];
            s_se += m * (d1*d1 + d2*d2 + d3*d3 + d4*d4);
        }
    }

    // Wave-64 butterfly reduce.
    #pragma unroll
    for (int off = 32; off > 0; off >>= 1) {
        cnt   += __shfl_down(cnt,   off);
        s_se  += __shfl_down(s_se,  off);
        s_bce += __shfl_down(s_bce, off);
        s_bg  += __shfl_down(s_bg,  off);
    }

    __shared__ float4 lds[BLOCK / 64];
    const int wid = threadIdx.x >> 6;
    if ((threadIdx.x & 63) == 0)
        lds[wid] = make_float4(cnt, s_se, s_bce, s_bg);
    __syncthreads();
    if (threadIdx.x == 0) {
        float4 a = lds[0];
        #pragma unroll
        for (int w = 1; w < BLOCK / 64; ++w) {
            a.x += lds[w].x; a.y += lds[w].y; a.z += lds[w].z; a.w += lds[w].w;
        }
        part[blockIdx.x] = a;                 // unconditional: deterministic
    }
}

// Stage 2: one block reduces the per-block partials and emits the scalar.
__global__ void mloss_final(const float4* __restrict__ part, int nparts,
                            float* __restrict__ out, float inv_total) {
    float cnt = 0.f, s_se = 0.f, s_bce = 0.f, s_bg = 0.f;
    for (int i = threadIdx.x; i < nparts; i += BLOCK) {
        float4 v = part[i];
        cnt += v.x; s_se += v.y; s_bce += v.z; s_bg += v.w;
    }
    #pragma unroll
    for (int off = 32; off > 0; off >>= 1) {
        cnt   += __shfl_down(cnt,   off);
        s_se  += __shfl_down(s_se,  off);
        s_bce += __shfl_down(s_bce, off);
        s_bg  += __shfl_down(s_bg,  off);
    }
    __shared__ float4 lds[BLOCK / 64];
    const int wid = threadIdx.x >> 6;
    if ((threadIdx.x & 63) == 0)
        lds[wid] = make_float4(cnt, s_se, s_bce, s_bg);
    __syncthreads();
    if (threadIdx.x == 0) {
        float4 a = lds[0];
        #pragma unroll
        for (int w = 1; w < BLOCK / 64; ++w) {
            a.x += lds[w].x; a.y += lds[w].y; a.z += lds[w].z; a.w += lds[w].w;
        }
        float f = a.x;
        float scale = 1.f + 1.f / f;
        float diff_box = scale * a.y / (f * 4.f);
        float diff_c   = scale * a.z / f;
        float diff_bg  = ALPHA * a.w * inv_total;
        out[0] = diff_box + diff_c + diff_bg;
    }
}

extern "C" void kernel_launch(void* const* d_in, const int* in_sizes, int n_in,
                              void* d_out, int out_size, void* d_ws, size_t ws_size,
                              hipStream_t stream) {
    const float* x = (const float*)d_in[0];
    const float* y = (const float*)d_in[1];
    float* out   = (float*)d_out;
    float4* part = (float4*)d_ws;

    int total  = in_sizes[0];        // B*N*C = 27,688,960
    int nrows  = total / 5;          // 5,537,792
    int ntiles = total / 1280;       // 21,632 tiles of 320 float4 (exact here)

    // 2 tiles per wave, 4 waves/block -> 8 tiles/block. Exact when
    // ntiles % 8 == 0 (true here: grid = 2704); else fallback loop.
    int grid;
    if (ntiles % 8 == 0) {
        grid = ntiles / 8;
    } else {
        grid = (ntiles / 2 + 3) / 4;
        if (grid < 256)  grid = 256;
    }
    if (grid > 8192) grid = 8192;    // fallback-path cap only
    int wscap = (int)(ws_size / sizeof(float4));
    if (grid > wscap) grid = wscap;

    mloss_partial<<<grid, BLOCK, 0, stream>>>((const float4*)x, (const float4*)y,
                                              x, y, part, ntiles, nrows);
    mloss_final<<<1, BLOCK, 0, stream>>>(part, grid, out, 1.0f / (float)nrows);
}